// Round 19
// baseline (858.478 us; speedup 1.0000x reference)
//
#include <hip/hip_runtime.h>
#include <hip/hip_fp16.h>
#include <math.h>

// MaxSim contrastive loss, MI355X.
// Round-19: fused pos/neg (r18, counter-best) + BK=64 single-buffered tiles.
// Lever validated by r14->r18: dur tracks phase-slot count x per-slot cost;
// more work per slot wins. This round halves phases (16 at BK=64) at the
// same 48KB LDS by dropping double-buffering: COMPUTE -> barrier -> STORE ->
// barrier (2 barriers/phase, same 32 total as r18). 32 MFMA/wave/phase
// amortizes the once-per-phase exposed load latency over 2x the work.
// Components verified: r14 BK=64 XOR-swizzled layout + staging map, r18
// fused ssq/epilogue/logits, XCD-bijective swizzle (1024 = 8 x 128).

constexpr int NB = 128;
constexpr int LQ = 256;
constexpr int LK = 512;
constexpr int DD = 1024;

#define TEMP_INV 20.0f
#define EPSN 1e-12f

typedef __fp16 fp16x2 __attribute__((ext_vector_type(2)));   // cvt_pkrtz return
typedef _Float16 f16x8 __attribute__((ext_vector_type(8)));  // MFMA operand
typedef float f32x4 __attribute__((ext_vector_type(4)));

#define BM 128
#define BN 128
#define BK 64
#define KITERS 16   // DD/BK

__device__ inline f16x8 cvt8(float4 a, float4 b) {
  union { f16x8 v; fp16x2 h[4]; } u;
  u.h[0] = __builtin_amdgcn_cvt_pkrtz(a.x, a.y);
  u.h[1] = __builtin_amdgcn_cvt_pkrtz(a.z, a.w);
  u.h[2] = __builtin_amdgcn_cvt_pkrtz(b.x, b.y);
  u.h[3] = __builtin_amdgcn_cvt_pkrtz(b.z, b.w);
  return u.v;
}

__global__ __launch_bounds__(512, 4) void maxsim_kernel(
    const float* __restrict__ q, const float* __restrict__ pk,
    const float* __restrict__ nk, const int* __restrict__ pmask,
    const int* __restrict__ nmask, float* __restrict__ part) {
  __shared__ _Float16 __align__(16) As[BM * BK];   // 16 KB
  __shared__ _Float16 __align__(16) Bps[BN * BK];  // 16 KB
  __shared__ _Float16 __align__(16) Bns[BN * BK];  // 16 KB  (48 KB, 1-buf)

  // XCD-aware bijective swizzle: 1024 blocks = 8 XCDs x 128
  const int bid = blockIdx.x;
  const int sw = (bid & 7) * 128 + (bid >> 3);
  const int b = sw >> 3;         // batch (8 blocks/batch)
  const int x = sw & 7;
  const int mt = x >> 2;         // 0..1  (q tile)
  const int nt = x & 3;          // 0..3  (key tile, both pos & neg)

  const float* Ag = q + ((size_t)b * LQ + mt * BM) * DD;
  const float* Pg = pk + ((size_t)b * LK + nt * BN) * DD;
  const float* Ng = nk + ((size_t)b * LK + nt * BN) * DD;

  const int tid = threadIdx.x;
  const int lane = tid & 63;
  const int w = tid >> 6;        // 0..7
  const int wr = w >> 1;         // 0..3 : A rows wr*32 + [0,32)
  const int wc = w & 1;          // 0..1 : B rows wc*64 + [0,64)
  const int frow = lane & 15;
  const int kgrp = lane >> 4;    // 0..3

  // staging map (r14-verified): thread t -> rows (t>>3)+64i (i=0,1),
  // 16B chunk sc = t&7; XOR-swizzled column offset.
  const int srow0 = tid >> 3;    // 0..63
  const int sc = tid & 7;
  const int cofs = ((sc ^ (srow0 & 7)) << 3);  // (srow0+64)&7 == srow0&7

  const float* pA0 = Ag + (size_t)srow0 * DD + sc * 8;
  const float* pA1 = Ag + (size_t)(srow0 + 64) * DD + sc * 8;
  const float* pP0 = Pg + (size_t)srow0 * DD + sc * 8;
  const float* pP1 = Pg + (size_t)(srow0 + 64) * DD + sc * 8;
  const float* pN0 = Ng + (size_t)srow0 * DD + sc * 8;
  const float* pN1 = Ng + (size_t)(srow0 + 64) * DD + sc * 8;

  float ssqA[2] = {0.f, 0.f};
  float ssqP[2] = {0.f, 0.f};
  float ssqN[2] = {0.f, 0.f};
  f32x4 accp[2][4] = {};
  f32x4 accn[2][4] = {};

  auto LOADS = [&](int it, float4 (&a)[4], float4 (&p)[4], float4 (&n)[4]) {
    const int koff = it * BK;    // compile-time after unroll -> imm offsets
    a[0] = *(const float4*)(pA0 + koff); a[1] = *(const float4*)(pA0 + koff + 4);
    a[2] = *(const float4*)(pA1 + koff); a[3] = *(const float4*)(pA1 + koff + 4);
    p[0] = *(const float4*)(pP0 + koff); p[1] = *(const float4*)(pP0 + koff + 4);
    p[2] = *(const float4*)(pP1 + koff); p[3] = *(const float4*)(pP1 + koff + 4);
    n[0] = *(const float4*)(pN0 + koff); n[1] = *(const float4*)(pN0 + koff + 4);
    n[2] = *(const float4*)(pN1 + koff); n[3] = *(const float4*)(pN1 + koff + 4);
  };
  auto sq4 = [](float4 v) {
    return v.x * v.x + v.y * v.y + v.z * v.z + v.w * v.w;
  };
  auto STORE = [&](float4 (&a)[4], float4 (&p)[4], float4 (&n)[4]) {
    #pragma unroll
    for (int i = 0; i < 2; ++i) {
      ssqA[i] += sq4(a[2 * i]) + sq4(a[2 * i + 1]);
      ssqP[i] += sq4(p[2 * i]) + sq4(p[2 * i + 1]);
      ssqN[i] += sq4(n[2 * i]) + sq4(n[2 * i + 1]);
      const int ro = (srow0 + 64 * i) * BK + cofs;
      *(f16x8*)&As[ro] = cvt8(a[2 * i], a[2 * i + 1]);
      *(f16x8*)&Bps[ro] = cvt8(p[2 * i], p[2 * i + 1]);
      *(f16x8*)&Bns[ro] = cvt8(n[2 * i], n[2 * i + 1]);
    }
  };
  auto COMPUTE = [&]() {
    __builtin_amdgcn_s_setprio(1);
    #pragma unroll
    for (int ks = 0; ks < 2; ++ks) {
      const int ch = ks * 4 + kgrp;
      f16x8 af[2], bp[4], bn[4];
      #pragma unroll
      for (int m = 0; m < 2; ++m) {
        const int row = wr * 32 + m * 16 + frow;
        af[m] = *(const f16x8*)&As[row * BK + ((ch ^ (row & 7)) << 3)];
      }
      #pragma unroll
      for (int n_ = 0; n_ < 4; ++n_) {
        const int row = wc * 64 + n_ * 16 + frow;
        const int ro = row * BK + ((ch ^ (row & 7)) << 3);
        bp[n_] = *(const f16x8*)&Bps[ro];
        bn[n_] = *(const f16x8*)&Bns[ro];
      }
      #pragma unroll
      for (int m = 0; m < 2; ++m)
        #pragma unroll
        for (int n_ = 0; n_ < 4; ++n_) {
          accp[m][n_] = __builtin_amdgcn_mfma_f32_16x16x32_f16(af[m], bp[n_], accp[m][n_], 0, 0, 0);
          accn[m][n_] = __builtin_amdgcn_mfma_f32_16x16x32_f16(af[m], bn[n_], accn[m][n_], 0, 0, 0);
        }
    }
    __builtin_amdgcn_s_setprio(0);
  };

  {
    float4 a[4], p[4], n[4];
    LOADS(0, a, p, n);
    STORE(a, p, n);
  }
  __syncthreads();

  #pragma unroll
  for (int it = 0; it < KITERS; ++it) {
    float4 a[4], p[4], n[4];
    if (it < KITERS - 1) LOADS(it + 1, a, p, n);  // imm-offset, issue early
    __builtin_amdgcn_sched_barrier(0);
    COMPUTE();
    __syncthreads();            // all reads done before tiles overwritten
    if (it < KITERS - 1) {
      STORE(a, p, n);
      __syncthreads();          // writes visible before next COMPUTE
    }
  }

  // ---- epilogue: norms, column scales, row-max (r18-verified algebra) ----
  #pragma unroll
  for (int off = 1; off < 8; off <<= 1) {
    #pragma unroll
    for (int i = 0; i < 2; ++i) {
      ssqA[i] += __shfl_xor(ssqA[i], off);
      ssqP[i] += __shfl_xor(ssqP[i], off);
      ssqN[i] += __shfl_xor(ssqN[i], off);
    }
  }

  // aux aliased onto As (4096 f16 = 2048 floats; need 896). Final COMPUTE's
  // reads are barrier-separated (loop's post-COMPUTE __syncthreads).
  float* const aux = reinterpret_cast<float*>(&As[0]);
  float* const invA_s = aux;            // [128]
  float* const cscP = aux + 128;        // [128]
  float* const cscN = aux + 256;        // [128]
  float* const rmaxP = aux + 384;       // [128][2]
  float* const rmaxN = aux + 640;       // [128][2]

  if (sc == 0) {
    #pragma unroll
    for (int i = 0; i < 2; ++i) {
      const int row = srow0 + 64 * i;
      invA_s[row] = 1.0f / fmaxf(sqrtf(ssqA[i]), EPSN);
      const int key = nt * BN + row;
      cscP[row] = (pmask[(size_t)b * LK + key] ? 1.0f : 0.0f) /
                  fmaxf(sqrtf(ssqP[i]), EPSN);
      cscN[row] = (nmask[(size_t)b * LK + key] ? 1.0f : 0.0f) /
                  fmaxf(sqrtf(ssqN[i]), EPSN);
    }
  }
  __syncthreads();

  float vmp[2][4], vmn[2][4];
  #pragma unroll
  for (int m = 0; m < 2; ++m)
    #pragma unroll
    for (int r = 0; r < 4; ++r) { vmp[m][r] = -INFINITY; vmn[m][r] = -INFINITY; }
  #pragma unroll
  for (int n_ = 0; n_ < 4; ++n_) {
    const int col = wc * 64 + n_ * 16 + frow;
    const float sp = cscP[col];
    const float sn = cscN[col];
    #pragma unroll
    for (int m = 0; m < 2; ++m)
      #pragma unroll
      for (int r = 0; r < 4; ++r) {
        vmp[m][r] = fmaxf(vmp[m][r], accp[m][n_][r] * sp);
        vmn[m][r] = fmaxf(vmn[m][r], accn[m][n_][r] * sn);
      }
  }
  #pragma unroll
  for (int off = 1; off < 16; off <<= 1)
    #pragma unroll
    for (int m = 0; m < 2; ++m)
      #pragma unroll
      for (int r = 0; r < 4; ++r) {
        vmp[m][r] = fmaxf(vmp[m][r], __shfl_xor(vmp[m][r], off));
        vmn[m][r] = fmaxf(vmn[m][r], __shfl_xor(vmn[m][r], off));
      }
  if ((lane & 15) == 0) {
    #pragma unroll
    for (int m = 0; m < 2; ++m)
      #pragma unroll
      for (int r = 0; r < 4; ++r) {
        const int row = wr * 32 + m * 16 + kgrp * 4 + r;
        rmaxP[row * 2 + wc] = vmp[m][r];
        rmaxN[row * 2 + wc] = vmn[m][r];
      }
  }
  __syncthreads();
  if (tid < BM) {
    const float ia = invA_s[tid];
    const float vP = fmaxf(rmaxP[tid * 2], rmaxP[tid * 2 + 1]) * ia;
    const float vN = fmaxf(rmaxN[tid * 2], rmaxN[tid * 2 + 1]) * ia;
    part[(((size_t)0 * NB + b) * 4 + nt) * LQ + mt * BM + tid] = vP;
    part[(((size_t)1 * NB + b) * 4 + nt) * LQ + mt * BM + tid] = vN;
  }
}

// ---------------- logits + softplus per batch (r14/r18-verified) ----------
__global__ __launch_bounds__(256) void logits_kernel(
    const float* __restrict__ part, const int* __restrict__ qmask,
    float* __restrict__ nll) {
  int b = blockIdx.x;
  int t = threadIdx.x;  // = lq
  float mp = -INFINITY, mn = -INFINITY;
  #pragma unroll
  for (int ntile = 0; ntile < 4; ++ntile) {
    mp = fmaxf(mp, part[(((size_t)0 * NB + b) * 4 + ntile) * LQ + t]);
    mn = fmaxf(mn, part[(((size_t)1 * NB + b) * 4 + ntile) * LQ + t]);
  }
  float qm = qmask[(size_t)b * LQ + t] ? 1.0f : 0.0f;
  float p = mp * qm;  // 1/|q| already folded into part
  float n = mn * qm;
  #pragma unroll
  for (int o = 32; o; o >>= 1) { p += __shfl_down(p, o); n += __shfl_down(n, o); }
  __shared__ float sp[4], sn[4];
  int lane = t & 63, w = t >> 6;
  if (lane == 0) { sp[w] = p; sn[w] = n; }
  __syncthreads();
  if (t == 0) {
    float ps = sp[0] + sp[1] + sp[2] + sp[3];
    float ns = sn[0] + sn[1] + sn[2] + sn[3];
    float z = (ns - ps) * TEMP_INV;
    nll[b] = z > 0.0f ? z + log1pf(expf(-z)) : log1pf(expf(z));
  }
}

__global__ void finalize_kernel(const float* __restrict__ nll, float* __restrict__ out) {
  __shared__ float s[128];
  int t = threadIdx.x;
  s[t] = nll[t];
  __syncthreads();
  #pragma unroll
  for (int o = 64; o; o >>= 1) {
    if (t < o) s[t] += s[t + o];
    __syncthreads();
  }
  if (t == 0) out[0] = s[0] * (1.0f / 128.0f);
}

extern "C" void kernel_launch(void* const* d_in, const int* in_sizes, int n_in,
                              void* d_out, int out_size, void* d_ws, size_t ws_size,
                              hipStream_t stream) {
  const float* q = (const float*)d_in[0];
  const float* pk = (const float*)d_in[1];
  const float* nk = (const float*)d_in[2];
  const int* qm = (const int*)d_in[3];
  const int* pm = (const int*)d_in[4];
  const int* nm = (const int*)d_in[5];

  float* ws = (float*)d_ws;
  float* part = ws;                // 262144 floats: [kt][b][nt][lq]
  float* nll = part + 262144;      // 128 floats

  maxsim_kernel<<<1024, 512, 0, stream>>>(q, pk, nk, pm, nm, part);
  logits_kernel<<<NB, 256, 0, stream>>>(part, qm, nll);
  finalize_kernel<<<1, 128, 0, stream>>>(nll, (float*)d_out);
}

// Round 20
// 181.348 us; speedup vs baseline: 4.7339x; 4.7339x over previous
//
#include <hip/hip_runtime.h>
#include <hip/hip_fp16.h>
#include <math.h>

// MaxSim contrastive loss, MI355X — FINAL champion (round-15 kernel, verified
// absmax 0.0, bench 180.5us). Structure: f16 LDS BK=32 double-buffered GEMM,
// merged-row XOR LDS layout (0 bank conflicts), register staging with fused
// sum-of-squares norms, fully unrolled K-loop (imm-offset loads), setprio
// around MFMA, XCD-bijective block swizzle (FETCH 787->328MB), fused
// column-scale+row-max epilogue folding 1/|q| and (1/|k|)*mask.
// Post-r19 diagnosis locked this in: single-buffer fusion spilled (WRITE 1.9GB
// scratch); counted-vmcnt DMA pipelines and occupancy pushes all regressed.

constexpr int NB = 128;
constexpr int LQ = 256;
constexpr int LK = 512;
constexpr int DD = 1024;

#define TEMP_INV 20.0f
#define EPSN 1e-12f

typedef __fp16 fp16x2 __attribute__((ext_vector_type(2)));   // cvt_pkrtz return
typedef _Float16 f16x8 __attribute__((ext_vector_type(8)));  // MFMA operand
typedef float f32x4 __attribute__((ext_vector_type(4)));

#define BM 128
#define BN 128
#define BK 32
#define KITERS (DD / BK)   // 32

__device__ inline f16x8 cvt8(float4 a, float4 b) {
  union { f16x8 v; fp16x2 h[4]; } u;
  u.h[0] = __builtin_amdgcn_cvt_pkrtz(a.x, a.y);
  u.h[1] = __builtin_amdgcn_cvt_pkrtz(a.z, a.w);
  u.h[2] = __builtin_amdgcn_cvt_pkrtz(b.x, b.y);
  u.h[3] = __builtin_amdgcn_cvt_pkrtz(b.z, b.w);
  return u.v;
}

// merged-row LDS index (in f16 units): two K=32 rows per 128B line.
// row 0..127, ch 0..3 (8-f16 chunk of the row's 32 K-cols).
__device__ __forceinline__ int lidx(int row, int ch) {
  const int line = row >> 1;
  const int slot = ((ch | ((row & 1) << 2)) ^ (line & 7));
  return line * 64 + slot * 8;
}

__global__ __launch_bounds__(512, 4) void maxsim_kernel(
    const float* __restrict__ q, const float* __restrict__ pk,
    const float* __restrict__ nk, const int* __restrict__ pmask,
    const int* __restrict__ nmask, float* __restrict__ part) {
  __shared__ _Float16 __align__(16) As[2][BM * BK];  // 2 x 8 KB
  __shared__ _Float16 __align__(16) Bs[2][BN * BK];  // 2 x 8 KB  (32 KB total)

  // XCD-aware bijective swizzle (r11/r12-verified): 2048 = 8 XCDs x 256.
  const int bid = blockIdx.x;
  const int sw = (bid & 7) * 256 + (bid >> 3);
  const int b = sw >> 4;         // batch
  const int x = sw & 15;
  const int mt = x >> 3;         // 0..1  (q tile)
  const int nt = (x >> 1) & 3;   // 0..3  (key tile)
  const int kt = x & 1;          // 0=pos 1=neg

  const float* kbase = kt ? nk : pk;
  const int* mbase = kt ? nmask : pmask;

  const float* Ag = q + ((size_t)b * LQ + mt * BM) * DD;
  const float* Bg = kbase + ((size_t)b * LK + nt * BN) * DD;

  const int tid = threadIdx.x;
  const int lane = tid & 63;
  const int w = tid >> 6;        // 0..7
  const int wr = w >> 1;         // 0..3 : rows wr*32 + [0,32)
  const int wc = w & 1;          // 0..1 : cols wc*64 + [0,64)
  const int frow = lane & 15;
  const int kgrp = lane >> 4;    // 0..3

  // staging map: thread t -> row t>>2 (0..127), 8-f16 chunk t&3
  const int rowS = tid >> 2;
  const int chS = tid & 3;
  const float* pA = Ag + (size_t)rowS * DD + chS * 8;
  const float* pB = Bg + (size_t)rowS * DD + chS * 8;
  const int sidx = lidx(rowS, chS);   // per-thread constant store index

  float ssqA = 0.f, ssqB = 0.f;
  f32x4 acc[2][4] = {};

  auto LOADS = [&](int it, float4& a0, float4& a1, float4& b0, float4& b1) {
    const int koff = it * BK;    // compile-time after unroll -> imm offsets
    a0 = *(const float4*)(pA + koff);
    a1 = *(const float4*)(pA + koff + 4);
    b0 = *(const float4*)(pB + koff);
    b1 = *(const float4*)(pB + koff + 4);
  };
  auto STORE = [&](int bsel, float4 a0, float4 a1, float4 b0, float4 b1) {
    ssqA += a0.x * a0.x + a0.y * a0.y + a0.z * a0.z + a0.w * a0.w +
            a1.x * a1.x + a1.y * a1.y + a1.z * a1.z + a1.w * a1.w;
    ssqB += b0.x * b0.x + b0.y * b0.y + b0.z * b0.z + b0.w * b0.w +
            b1.x * b1.x + b1.y * b1.y + b1.z * b1.z + b1.w * b1.w;
    *(f16x8*)&As[bsel][sidx] = cvt8(a0, a1);
    *(f16x8*)&Bs[bsel][sidx] = cvt8(b0, b1);
  };
  auto COMPUTE = [&](int bsel) {
    __builtin_amdgcn_s_setprio(1);
    f16x8 af[2], bf[4];
    #pragma unroll
    for (int m = 0; m < 2; ++m)
      af[m] = *(const f16x8*)&As[bsel][lidx(wr * 32 + m * 16 + frow, kgrp)];
    #pragma unroll
    for (int n = 0; n < 4; ++n)
      bf[n] = *(const f16x8*)&Bs[bsel][lidx(wc * 64 + n * 16 + frow, kgrp)];
    #pragma unroll
    for (int m = 0; m < 2; ++m)
      #pragma unroll
      for (int n = 0; n < 4; ++n)
        acc[m][n] = __builtin_amdgcn_mfma_f32_16x16x32_f16(af[m], bf[n], acc[m][n], 0, 0, 0);
    __builtin_amdgcn_s_setprio(0);
  };

  {
    float4 a0, a1, b0, b1;
    LOADS(0, a0, a1, b0, b1);
    STORE(0, a0, a1, b0, b1);
  }
  __syncthreads();

  #pragma unroll
  for (int it = 0; it < KITERS - 1; ++it) {
    float4 a0, a1, b0, b1;
    LOADS(it + 1, a0, a1, b0, b1);   // imm-offset loads, issue early
    __builtin_amdgcn_sched_barrier(0);
    COMPUTE(it & 1);
    STORE((it & 1) ^ 1, a0, a1, b0, b1);
    __syncthreads();
  }
  COMPUTE(1);                // tile 31 (buf 1)

  // ---- epilogue: norms, column scales, row-max ----
  ssqA += __shfl_xor(ssqA, 1); ssqA += __shfl_xor(ssqA, 2);
  ssqB += __shfl_xor(ssqB, 1); ssqB += __shfl_xor(ssqB, 2);

  // aux arrays aliased onto As[0] (2048 floats avail; need 512);
  // final COMPUTE read As[1]/Bs[1] only.
  float* const aux = reinterpret_cast<float*>(&As[0][0]);
  float* const csc = aux;             // [BN]  (1/|k|)*mask
  float* const invA_s = aux + BN;     // [BM]  1/|q|
  float* const rmax = aux + BN + BM;  // [BM][2]

  if (chS == 0) {
    invA_s[rowS] = 1.0f / fmaxf(sqrtf(ssqA), EPSN);
    const int key = nt * BN + rowS;
    csc[rowS] = (mbase[(size_t)b * LK + key] ? 1.0f : 0.0f) /
                fmaxf(sqrtf(ssqB), EPSN);
  }
  __syncthreads();

  float vmax[2][4];
  #pragma unroll
  for (int m = 0; m < 2; ++m)
    #pragma unroll
    for (int r = 0; r < 4; ++r) vmax[m][r] = -INFINITY;
  #pragma unroll
  for (int n = 0; n < 4; ++n) {
    const float s = csc[wc * 64 + n * 16 + frow];
    #pragma unroll
    for (int m = 0; m < 2; ++m)
      #pragma unroll
      for (int r = 0; r < 4; ++r)
        vmax[m][r] = fmaxf(vmax[m][r], acc[m][n][r] * s);
  }
  #pragma unroll
  for (int off = 1; off < 16; off <<= 1)
    #pragma unroll
    for (int m = 0; m < 2; ++m)
      #pragma unroll
      for (int r = 0; r < 4; ++r)
        vmax[m][r] = fmaxf(vmax[m][r], __shfl_xor(vmax[m][r], off));
  if ((lane & 15) == 0) {
    #pragma unroll
    for (int m = 0; m < 2; ++m)
      #pragma unroll
      for (int r = 0; r < 4; ++r)
        rmax[(wr * 32 + m * 16 + kgrp * 4 + r) * 2 + wc] = vmax[m][r];
  }
  __syncthreads();
  if (tid < BM) {
    const float v = fmaxf(rmax[tid * 2], rmax[tid * 2 + 1]) * invA_s[tid];
    part[(((size_t)kt * NB + b) * 4 + nt) * LQ + mt * BM + tid] = v;
  }
}

// ---------------- logits + softplus per batch ----------------
__global__ __launch_bounds__(256) void logits_kernel(
    const float* __restrict__ part, const int* __restrict__ qmask,
    float* __restrict__ nll) {
  int b = blockIdx.x;
  int t = threadIdx.x;  // = lq
  float mp = -INFINITY, mn = -INFINITY;
  #pragma unroll
  for (int ntile = 0; ntile < 4; ++ntile) {
    mp = fmaxf(mp, part[(((size_t)0 * NB + b) * 4 + ntile) * LQ + t]);
    mn = fmaxf(mn, part[(((size_t)1 * NB + b) * 4 + ntile) * LQ + t]);
  }
  float qm = qmask[(size_t)b * LQ + t] ? 1.0f : 0.0f;
  float p = mp * qm;  // 1/|q| already folded into part
  float n = mn * qm;
  #pragma unroll
  for (int o = 32; o; o >>= 1) { p += __shfl_down(p, o); n += __shfl_down(n, o); }
  __shared__ float sp[4], sn[4];
  int lane = t & 63, w = t >> 6;
  if (lane == 0) { sp[w] = p; sn[w] = n; }
  __syncthreads();
  if (t == 0) {
    float ps = sp[0] + sp[1] + sp[2] + sp[3];
    float ns = sn[0] + sn[1] + sn[2] + sn[3];
    float z = (ns - ps) * TEMP_INV;
    nll[b] = z > 0.0f ? z + log1pf(expf(-z)) : log1pf(expf(z));
  }
}

__global__ void finalize_kernel(const float* __restrict__ nll, float* __restrict__ out) {
  __shared__ float s[128];
  int t = threadIdx.x;
  s[t] = nll[t];
  __syncthreads();
  #pragma unroll
  for (int o = 64; o; o >>= 1) {
    if (t < o) s[t] += s[t + o];
    __syncthreads();
  }
  if (t == 0) out[0] = s[0] * (1.0f / 128.0f);
}

extern "C" void kernel_launch(void* const* d_in, const int* in_sizes, int n_in,
                              void* d_out, int out_size, void* d_ws, size_t ws_size,
                              hipStream_t stream) {
  const float* q = (const float*)d_in[0];
  const float* pk = (const float*)d_in[1];
  const float* nk = (const float*)d_in[2];
  const int* qm = (const int*)d_in[3];
  const int* pm = (const int*)d_in[4];
  const int* nm = (const int*)d_in[5];

  float* ws = (float*)d_ws;
  float* part = ws;                // 262144 floats: [kt][b][nt][lq]
  float* nll = part + 262144;      // 128 floats

  maxsim_kernel<<<2048, 512, 0, stream>>>(q, pk, nk, pm, nm, part);
  logits_kernel<<<NB, 256, 0, stream>>>(part, qm, nll);
  finalize_kernel<<<1, 128, 0, stream>>>(nll, (float*)d_out);
}